// Round 1
// baseline (15.094 us; speedup 1.0000x reference)
//
#include <hip/hip_runtime.h>
#include <hip/hip_bf16.h>

// Reference:
//   scores = q @ k^T / sqrt(D); attn = softmax(scores, axis=-1)
//   out[b,i,d] = v[b,i,d] * sum_j attn[b,i,j]
// sum_j softmax(.)[j] == 1 exactly (to fp32 rounding ~1e-5), so out == v.
// The whole attention computation is dead code; the kernel is a d2d copy.

extern "C" void kernel_launch(void* const* d_in, const int* in_sizes, int n_in,
                              void* d_out, int out_size, void* d_ws, size_t ws_size,
                              hipStream_t stream) {
    const float* v = (const float*)d_in[2];   // inputs: q, k, v
    float* out = (float*)d_out;
    (void)in_sizes; (void)n_in; (void)d_ws; (void)ws_size;
    hipMemcpyAsync(out, v, (size_t)out_size * sizeof(float),
                   hipMemcpyDeviceToDevice, stream);
}